// Round 9
// baseline (261.111 us; speedup 1.0000x reference)
//
#include <hip/hip_runtime.h>
#include <math.h>

// ---------------------------------------------------------------------------
// SparseMoE — MFMA kernel, MI355X (gfx950).  B=8 S=4096 D=256 F=512 E=8 K=2.
// r18 (revert to r14 skeleton after r16/r17 deferred-pipeline spills;
//      WRITE_SIZE 86MB proved arch+acc>128 under launch_bounds(512,4)):
//   * Both GEMMs moved to 32x32x16 MFMA: halves MFMA instruction count
//     (64->32/wave/iter) and halves LDS b128 reads; 32x32 pipe is ~15%
//     faster per FLOP. Wave wv: GEMM1 tile (fi=wv&3 f-32-slice, mi=wv>>2
//     token-32-slice); GEMM2 (di=wv&3 d-64-pair, mi token-slice).
//     Cost: W L2 traffic 2x (mi-duplication) — L2 has headroom.
//   * r14 pipeline kept: 1 lgkm barrier/iter, dbuf Hsb, w1 half prefetched
//     one iter ahead (loop-carried 32 regs), w2 first-2kc pre-issued before
//     the barrier, rest streamed under MFMAs.
//   * Layouts: A row=l&31,k=(l>>5)*8+j; C/D col=l&31,row=(reg&3)+8(reg>>2)
//     +4(l>>5) (guide-verified m74/m101). LN: shfl over 32 lo-lanes + 4-di
//     LDS combine.
// Falsifier: WRITE_SIZE > 50MB => spill => revert verbatim r14.
// Router fp64 deterministic. ws ~5.3 MB.
// ---------------------------------------------------------------------------

#define B_ 8
#define S_ 4096
#define D_ 256
#define F_ 512
#define E_ 8

typedef short bf16x8 __attribute__((ext_vector_type(8)));
typedef float f32x4 __attribute__((ext_vector_type(4)));
typedef float f32x16 __attribute__((ext_vector_type(16)));

static __device__ __forceinline__ unsigned short f2bf(float f) {
    union { float f; unsigned int i; } v; v.f = f;
    unsigned int x = v.i;
    return (unsigned short)((x + 0x7fffu + ((x >> 16) & 1u)) >> 16);  // RNE
}

// pack two f32 -> two bf16 (RNE), lo = s0, hi = s1
static __device__ __forceinline__ unsigned int cvt_pk_bf16(float s0, float s1) {
    unsigned int r;
    asm("v_cvt_pk_bf16_f32 %0, %1, %2" : "=v"(r) : "v"(s0), "v"(s1));
    return r;
}

// barrier that drains LDS ops only — global loads stay in flight.
static __device__ __forceinline__ void bar_lds() {
    asm volatile("s_waitcnt lgkmcnt(0)" ::: "memory");
    __builtin_amdgcn_s_barrier();
}

// GELU(v) = 0.5 v (1 + erf(v/sqrt2)); erf via A&S 7.1.26, |err|<=1.5e-7.
static __device__ __forceinline__ float gelu_f(float v) {
    float x = fabsf(v) * 0.70710678118654752f;
    float t = __builtin_amdgcn_rcpf(1.0f + 0.3275911f * x);
    float p = t * (0.254829592f +
              t * (-0.284496736f +
              t * (1.421413741f +
              t * (-1.453152027f +
              t * 1.061405429f))));
    float er = 1.0f - p * __expf(-x * x);
    er = __builtin_copysignf(er, v);
    return 0.5f * v * (1.0f + er);
}

// ---------------------------------------------------------------------------
// 1) k_prep: fused grid. Blocks [0,512): fp64 partial mean-reduction over S.
//    Blocks [512,1536): W1 [E][256][512] -> W1T [E][512][256] bf16.
//    Blocks [1536,2560): W2 [E][512][256] -> W2T [E][256][512] bf16.
// ---------------------------------------------------------------------------
__global__ void k_prep(const float* __restrict__ x,
                       double* __restrict__ partial,
                       const float* __restrict__ W1,
                       const float* __restrict__ W2,
                       unsigned short* __restrict__ W1T,
                       unsigned short* __restrict__ W2T) {
    int bid = blockIdx.x;
    if (bid < 512) {
        int b = bid >> 6;
        int c = bid & 63;
        int d = threadIdx.x;
        const float* p = x + ((size_t)(b * S_ + c * 64) * D_ + d);
        double acc = 0.0;
        #pragma unroll 8
        for (int i = 0; i < 64; ++i) acc += (double)p[(size_t)i * D_];
        partial[(size_t)bid * D_ + d] = acc;
        return;
    }
    __shared__ float tile[32][33];
    const float* src;
    unsigned short* dst;
    int R, C, cb, rb;
    if (bid < 1536) {
        int b2 = bid - 512;            // e(8) x by(8) x bx(16)
        int e = b2 >> 7, rem = b2 & 127;
        int by = rem >> 4, bx = rem & 15;
        R = 256; C = 512;
        src = W1 + (size_t)e * R * C;
        dst = W1T + (size_t)e * R * C;
        cb = bx * 32; rb = by * 32;
    } else {
        int b2 = bid - 1536;           // e(8) x by(16) x bx(8)
        int e = b2 >> 7, rem = b2 & 127;
        int by = rem >> 3, bx = rem & 7;
        R = 512; C = 256;
        src = W2 + (size_t)e * R * C;
        dst = W2T + (size_t)e * R * C;
        cb = bx * 32; rb = by * 32;
    }
    int tx = threadIdx.x & 31, ty = threadIdx.x >> 5;
    #pragma unroll
    for (int k = 0; k < 4; ++k)
        tile[ty + 8 * k][tx] = src[(size_t)(rb + ty + 8 * k) * C + cb + tx];
    __syncthreads();
    #pragma unroll
    for (int k = 0; k < 4; ++k)
        dst[(size_t)(cb + ty + 8 * k) * R + rb + tx] = f2bf(tile[tx][ty + 8 * k]);
}

// ---------------------------------------------------------------------------
// 2a) k_red2: 8 blocks (one per batch). Block bb: xs[d] = sum_c partial,
//     then logits lg[bb*8+e] (same fp64 order as before).
// ---------------------------------------------------------------------------
__global__ void k_red2(const double* __restrict__ partial,
                       const float* __restrict__ Wr,
                       const float* __restrict__ br,
                       double* __restrict__ lgout) {
    __shared__ double xs[256];
    int bb = blockIdx.x;
    int t = threadIdx.x;              // 0..255 = d
    double acc = 0.0;
    #pragma unroll 8
    for (int c = 0; c < 64; ++c)
        acc += partial[(size_t)(bb * 64 + c) * D_ + t];
    xs[t] = acc;
    __syncthreads();
    if (t < 8) {
        int e = t;
        double a2 = 0.0;
        for (int d = 0; d < D_; ++d)
            a2 += (xs[d] * (1.0 / (double)S_)) * (double)Wr[d * E_ + e];
        lgout[bb * 8 + e] = a2 + (double)br[e];
    }
}

// ---------------------------------------------------------------------------
// 2b) k_router: 1 tiny block. fp64 phases A/B (unchanged).
// ---------------------------------------------------------------------------
__global__ void k_router(const double* __restrict__ lgin,
                         float* __restrict__ route) {
    __shared__ double lg[64];
    __shared__ double rw[8][8];
    int t = threadIdx.x;
    if (t < 64) lg[t] = lgin[t];
    __syncthreads();
    if (t < 8) {
        int bb = t;
        double m = -1e300;
        for (int ee = 0; ee < 8; ++ee) m = fmax(m, lg[bb * 8 + ee]);
        double s = 0.0;
        double p[8];
        for (int ee = 0; ee < 8; ++ee) { p[ee] = exp(lg[bb * 8 + ee] - m); s += p[ee]; }
        for (int ee = 0; ee < 8; ++ee) rw[bb][ee] = p[ee] / s;
    }
    __syncthreads();
    if (t < 8) {
        int bb = t;
        const double capacity = 5120.0;
        double scale[8];
        for (int ee = 0; ee < 8; ++ee) {
            double load = 0.0;
            for (int b2 = 0; b2 < 8; ++b2) load += rw[b2][ee];
            load *= 4096.0;
            scale[ee] = load > capacity ? capacity / load : 1.0;
        }
        double v[8];
        double m = -1e300;
        for (int ee = 0; ee < 8; ++ee) { v[ee] = rw[bb][ee] * scale[ee]; m = fmax(m, v[ee]); }
        double s = 0.0;
        for (int ee = 0; ee < 8; ++ee) { v[ee] = exp(v[ee] - m); s += v[ee]; }
        for (int ee = 0; ee < 8; ++ee) v[ee] /= s;
        int i1 = 0;
        for (int ee = 1; ee < 8; ++ee) if (v[ee] > v[i1]) i1 = ee;
        int i2 = (i1 == 0) ? 1 : 0;
        for (int ee = 0; ee < 8; ++ee) { if (ee == i1) continue; if (v[ee] > v[i2]) i2 = ee; }
        double d21 = v[i2] - v[i1];
        double ed = exp(d21);
        double w1 = 1.0 / (1.0 + ed);
        double w2 = ed * w1;
        route[bb * 4 + 0] = (float)i1;
        route[bb * 4 + 1] = (float)i2;
        route[bb * 4 + 2] = (float)w1;
        route[bb * 4 + 3] = (float)w2;
    }
}

// ---------------------------------------------------------------------------
// 3) Main MFMA kernel: per block = (batch, 64-token tile). 512 x 512 thr.
//    32x32x16 MFMA. Per iter (it: sl=it>>2 expert, fb=it&3 128-f block):
//      GEMM1: wave (fi=wv&3, mi=wv>>2) computes H^T tile [32 f][32 tok],
//             16 kc-chunks (k=16 over D=256), w1 half0 prefetched one iter
//             ahead (loop-carried), half1 streamed.
//      GELU -> Hsb[wb][token][f] (4 b64 stores).
//      pre-issue w2 kc0-1 -> lgkm barrier ->
//      GEMM2: wave (di=wv&3, mi) computes Y tiles d=di*64+{0,32},
//             8 kc-chunks (k=16 over 128 f), w2 streamed, then prefetch
//             next iter's w1 half0.
//    Epilogue: register LayerNorm (shfl over 32 lo-lanes + 4-di combine).
// ---------------------------------------------------------------------------
__launch_bounds__(512, 4)
__global__ void k_moe_m(const float* __restrict__ xf,
                        const unsigned short* __restrict__ W1T,  // [E][F][D]
                        const unsigned short* __restrict__ W2T,  // [E][D][F]
                        const float* __restrict__ b1,
                        const float* __restrict__ b2,
                        const float* __restrict__ gamma,
                        const float* __restrict__ beta,
                        const float* __restrict__ route,
                        float* __restrict__ out) {
    __shared__ __align__(16) unsigned short Xsb[64][264];     // 33.8 KB
    __shared__ __align__(16) unsigned short Hsb[2][64][136];  // 34.8 KB dbuf
    __shared__ float gbuf[256], bbuf[256];
    __shared__ __align__(16) float rred[64][8];               // LN partials (2KB)

    const int t = threadIdx.x;        // 0..511
    const int wv = t >> 6;            // wave 0..7
    const int lane = t & 63;
    const int lo = lane & 31;         // 0..31
    const int hi = lane >> 5;         // 0..1
    const int fi = wv & 3;            // GEMM1: f-32-slice
    const int mi = wv >> 2;           // token-32-slice (both GEMMs)
    const int di = wv & 3;            // GEMM2: d-64-pair
    const int b = blockIdx.x & 7;     // XCD-aligned batch (W L2 locality)
    const int m0 = (blockIdx.x >> 3) * 64;

    if (t < 256) { gbuf[t] = gamma[t]; bbuf[t] = beta[t]; }

    const int e0i = (int)route[b * 4 + 0];
    const int e1i = (int)route[b * 4 + 1];
    const float rw0 = route[b * 4 + 2];
    const float rw1 = route[b * 4 + 3];

    // ---- stage X tile [64][256] as bf16, once ----
    {
        int row = t >> 3;
        int col0 = (t & 7) * 32;
        const float* src = xf + ((size_t)(b * S_ + m0 + row) * D_ + col0);
        #pragma unroll
        for (int jg = 0; jg < 4; ++jg) {
            float4 a0 = *(const float4*)(src + jg * 8);
            float4 a1 = *(const float4*)(src + jg * 8 + 4);
            union { unsigned int pk[4]; uint4 q; } o;
            o.pk[0] = cvt_pk_bf16(a0.x, a0.y);
            o.pk[1] = cvt_pk_bf16(a0.z, a0.w);
            o.pk[2] = cvt_pk_bf16(a1.x, a1.y);
            o.pk[3] = cvt_pk_bf16(a1.z, a1.w);
            *(uint4*)&Xsb[row][col0 + jg * 8] = o.q;
        }
    }

    f32x16 Yacc[2];
    #pragma unroll
    for (int j = 0; j < 2; ++j)
        #pragma unroll
        for (int r = 0; r < 16; ++r) Yacc[j][r] = 0.f;

    // ---- prologue: prefetch w1 half0 for it=0 (loop-carried 32 regs) ----
    bf16x8 w1h[8];
    {
        const unsigned short* w1p0 =
            W1T + ((size_t)(e0i * F_ + fi * 32 + lo)) * D_ + hi * 8;
        #pragma unroll
        for (int k = 0; k < 8; ++k)
            w1h[k] = *(const bf16x8*)(w1p0 + k * 16);
    }

    bar_lds();   // Xsb visible to all waves; pins w1h issue

    for (int it = 0; it < 8; ++it) {
        const int e  = (it >= 4) ? e1i : e0i;
        const float w = (it >= 4) ? rw1 : rw0;
        const int fb = it & 3;
        const int wb = it & 1;        // Hsb write buffer this iter

        const unsigned short* w1p =
            W1T + ((size_t)(e * F_ + fb * 128 + fi * 32 + lo)) * D_ + hi * 8;

        // ---- GEMM1: H^T[32 f][32 tok], k = 256 in 16 chunks ----
        f32x16 Hacc;
        #pragma unroll
        for (int r = 0; r < 16; ++r) Hacc[r] = 0.f;
        // half0: kc 0..7 (w1h prefetched one iter ago)
        #pragma unroll
        for (int k = 0; k < 8; ++k) {
            bf16x8 xa = *(const bf16x8*)&Xsb[mi * 32 + lo][k * 16 + hi * 8];
            Hacc = __builtin_amdgcn_mfma_f32_32x32x16_bf16(w1h[k], xa, Hacc, 0, 0, 0);
        }
        // half1: kc 8..15 streamed (loads overlap half0's MFMAs)
        #pragma unroll
        for (int k = 0; k < 8; ++k)
            w1h[k] = *(const bf16x8*)(w1p + (8 + k) * 16);
        #pragma unroll
        for (int k = 0; k < 8; ++k) {
            bf16x8 xa = *(const bf16x8*)&Xsb[mi * 32 + lo][(8 + k) * 16 + hi * 8];
            Hacc = __builtin_amdgcn_mfma_f32_32x32x16_bf16(w1h[k], xa, Hacc, 0, 0, 0);
        }

        // ---- GELU(+b1)*w -> Hsb[wb][token][f]; reg r: f_local =
        //      (r&3)+8*(r>>2)+4*hi, token = mi*32+lo ----
        #pragma unroll
        for (int q4 = 0; q4 < 4; ++q4) {
            int f0 = 8 * q4 + 4 * hi;                 // local f of this group
            float4 bb4 = *(const float4*)&b1[e * F_ + fb * 128 + fi * 32 + f0];
            float h0 = w * gelu_f(Hacc[q4 * 4 + 0] + bb4.x);
            float h1 = w * gelu_f(Hacc[q4 * 4 + 1] + bb4.y);
            float h2 = w * gelu_f(Hacc[q4 * 4 + 2] + bb4.z);
            float h3 = w * gelu_f(Hacc[q4 * 4 + 3] + bb4.w);
            uint2 q;
            q.x = cvt_pk_bf16(h0, h1);
            q.y = cvt_pk_bf16(h2, h3);
            *(uint2*)&Hsb[wb][mi * 32 + lo][fi * 32 + f0] = q;
        }

        // ---- pre-issue w2 kc0-1 (both d-tiles) before the barrier ----
        const unsigned short* w2p =
            W2T + ((size_t)(e * D_ + di * 64 + lo)) * F_ + fb * 128 + hi * 8;
        bf16x8 w2a0 = *(const bf16x8*)(w2p);
        bf16x8 w2b0 = *(const bf16x8*)(w2p + (size_t)32 * F_);
        bf16x8 w2a1 = *(const bf16x8*)(w2p + 16);
        bf16x8 w2b1 = *(const bf16x8*)(w2p + (size_t)32 * F_ + 16);

        bar_lds();   // Hsb[wb] visible; global loads stay in flight

        // ---- GEMM2: Y[d=di*64+{0,32}][tok], k = 128 f in 8 chunks ----
        #pragma unroll
        for (int kc = 0; kc < 8; ++kc) {
            bf16x8 ha = *(const bf16x8*)&Hsb[wb][mi * 32 + lo][kc * 16 + hi * 8];
            bf16x8 wa = (kc == 0) ? w2a0 : (kc == 1) ? w2a1
                        : *(const bf16x8*)(w2p + kc * 16);
            bf16x8 wbv = (kc == 0) ? w2b0 : (kc == 1) ? w2b1
                        : *(const bf16x8*)(w2p + (size_t)32 * F_ + kc * 16);
            Yacc[0] = __builtin_amdgcn_mfma_f32_32x32x16_bf16(ha, wa, Yacc[0], 0, 0, 0);
            Yacc[1] = __builtin_amdgcn_mfma_f32_32x32x16_bf16(ha, wbv, Yacc[1], 0, 0, 0);
        }

        // ---- prefetch next iter's w1 half0 (hidden under GEMM2/next GEMM1) --
        {
            const int itn = (it + 1) & 7;
            const int en = (itn >= 4) ? e1i : e0i;
            const int fbn = itn & 3;
            const unsigned short* w1pn =
                W1T + ((size_t)(en * F_ + fbn * 128 + fi * 32 + lo)) * D_ + hi * 8;
            #pragma unroll
            for (int k = 0; k < 8; ++k)
                w1h[k] = *(const bf16x8*)(w1pn + k * 16);
        }
    }

    // ---- Epilogue: register LayerNorm ----
    // lane holds Y[row][d]: row = mi*32 + (r&3)+8*(r>>2)+4*hi (16 rows),
    // d = di*64 + dt*32 + lo (2 per row).
    float bias2v[2];
    #pragma unroll
    for (int dt = 0; dt < 2; ++dt) {
        int d = di * 64 + dt * 32 + lo;
        bias2v[dt] = rw0 * b2[e0i * D_ + d] + rw1 * b2[e1i * D_ + d];
    }
    #pragma unroll
    for (int r = 0; r < 16; ++r) {
        int row = mi * 32 + (r & 3) + 8 * (r >> 2) + 4 * hi;
        const float* xr = xf + (size_t)(b * S_ + m0 + row) * D_;
        float s = 0.f, sq = 0.f;
        #pragma unroll
        for (int dt = 0; dt < 2; ++dt) {
            int d = di * 64 + dt * 32 + lo;
            float v = Yacc[dt][r] + bias2v[dt] + xr[d];
            Yacc[dt][r] = v;
            s += v; sq += v * v;
        }
        // reduce over the 32 lo-lanes (masks 1..16 stay within each half)
        s += __shfl_xor(s, 1);  sq += __shfl_xor(sq, 1);
        s += __shfl_xor(s, 2);  sq += __shfl_xor(sq, 2);
        s += __shfl_xor(s, 4);  sq += __shfl_xor(sq, 4);
        s += __shfl_xor(s, 8);  sq += __shfl_xor(sq, 8);
        s += __shfl_xor(s, 16); sq += __shfl_xor(sq, 16);
        if (lo == 0) { rred[row][di * 2] = s; rred[row][di * 2 + 1] = sq; }
    }
    bar_lds();
    #pragma unroll
    for (int r = 0; r < 16; ++r) {
        int row = mi * 32 + (r & 3) + 8 * (r >> 2) + 4 * hi;
        float4 p0 = *(const float4*)&rred[row][0];
        float4 p1 = *(const float4*)&rred[row][4];
        float s  = (p0.x + p0.z) + (p1.x + p1.z);
        float sq = (p0.y + p0.w) + (p1.y + p1.w);
        float mu = s * (1.0f / 256.0f);
        float var = sq * (1.0f / 256.0f) - mu * mu;
        float rstd = rsqrtf(var + 1e-5f);
        float* op = out + (size_t)(b * S_ + m0 + row) * D_;
        #pragma unroll
        for (int dt = 0; dt < 2; ++dt) {
            int d = di * 64 + dt * 32 + lo;
            op[d] = (Yacc[dt][r] - mu) * rstd * gbuf[d] + bbuf[d];
        }
    }
}

// ---------------------------------------------------------------------------
extern "C" void kernel_launch(void* const* d_in, const int* in_sizes, int n_in,
                              void* d_out, int out_size, void* d_ws, size_t ws_size,
                              hipStream_t stream) {
    const float* x     = (const float*)d_in[0];
    const float* Wr    = (const float*)d_in[1];
    const float* br    = (const float*)d_in[2];
    const float* W1    = (const float*)d_in[3];
    const float* b1    = (const float*)d_in[4];
    const float* W2    = (const float*)d_in[5];
    const float* b2    = (const float*)d_in[6];
    const float* gamma = (const float*)d_in[7];
    const float* beta  = (const float*)d_in[8];
    float* out = (float*)d_out;

    char* ws = (char*)d_ws;
    double* partial = (double*)ws;                               // 1 MB
    float* route  = (float*)(ws + 1064960);                      // 128 B
    double* lg    = (double*)(ws + 1065472);                     // 512 B
    unsigned short* W1T = (unsigned short*)(ws + 1081344);       // 2 MB [E][F][D]
    unsigned short* W2T = (unsigned short*)(ws + 3178496);       // 2 MB [E][D][F]
    // total ws usage: ~5.3 MB

    hipLaunchKernelGGL(k_prep, dim3(2560), dim3(256), 0, stream,
                       x, partial, W1, W2, W1T, W2T);
    hipLaunchKernelGGL(k_red2, dim3(8), dim3(256), 0, stream,
                       partial, Wr, br, lg);
    hipLaunchKernelGGL(k_router, dim3(1), dim3(64), 0, stream,
                       lg, route);
    hipLaunchKernelGGL(k_moe_m, dim3(512), dim3(512), 0, stream,
                       x, W1T, W2T, b1, b2, gamma, beta, route, out);
}

// Round 11
// 204.186 us; speedup vs baseline: 1.2788x; 1.2788x over previous
//
#include <hip/hip_runtime.h>
#include <math.h>

// ---------------------------------------------------------------------------
// SparseMoE — MFMA kernel, MI355X (gfx950).  B=8 S=4096 D=256 F=512 E=8 K=2.
// r20 = r19 resubmitted (round-10 bench died to an infra error, no data).
// r19 = r14 (proven best: main 95.7us, total 201.9us) + s_setprio around the
// MFMA clusters.  Session ledger:
//   r15 (32 waves/CU): FAILED — launch_bounds(512,8) caps 64 VGPR -> spill.
//   r16/r17 (deferred GEMM2): FAILED — w1f+w2f concurrent liveness >128
//     combined arch+acc -> spill (WRITE_SIZE 84-86MB).
//   r18 (32x32x16): FAILED — streamed w2 loads exposed (~6x200cyc/iter) +
//     16-deep single-accumulator MFMA chains; main 154us.
//   => The 16x16x32 shape with 8 independent acc chains and FULLY preloaded
//      w2f (32 regs, issued pre-GEMM1, live through it: 64 arch + 48 acc =
//      112 <= 128) is the latency-tolerant optimum found.
//   * setprio: 2 independent blocks/CU at arbitrary phases = T5's measured
//     regime (+4-7% attn, m191). Worst case ~-2%.
// Router fp64 deterministic. ws ~5.3 MB.
// ---------------------------------------------------------------------------

#define B_ 8
#define S_ 4096
#define D_ 256
#define F_ 512
#define E_ 8

typedef short bf16x8 __attribute__((ext_vector_type(8)));
typedef float f32x4 __attribute__((ext_vector_type(4)));

static __device__ __forceinline__ unsigned short f2bf(float f) {
    union { float f; unsigned int i; } v; v.f = f;
    unsigned int x = v.i;
    return (unsigned short)((x + 0x7fffu + ((x >> 16) & 1u)) >> 16);  // RNE
}

// pack two f32 -> two bf16 (RNE), lo = s0, hi = s1
static __device__ __forceinline__ unsigned int cvt_pk_bf16(float s0, float s1) {
    unsigned int r;
    asm("v_cvt_pk_bf16_f32 %0, %1, %2" : "=v"(r) : "v"(s0), "v"(s1));
    return r;
}

// barrier that drains LDS ops only — global loads stay in flight.
static __device__ __forceinline__ void bar_lds() {
    asm volatile("s_waitcnt lgkmcnt(0)" ::: "memory");
    __builtin_amdgcn_s_barrier();
}

// GELU(v) = 0.5 v (1 + erf(v/sqrt2)); erf via A&S 7.1.26, |err|<=1.5e-7.
static __device__ __forceinline__ float gelu_f(float v) {
    float x = fabsf(v) * 0.70710678118654752f;
    float t = __builtin_amdgcn_rcpf(1.0f + 0.3275911f * x);
    float p = t * (0.254829592f +
              t * (-0.284496736f +
              t * (1.421413741f +
              t * (-1.453152027f +
              t * 1.061405429f))));
    float er = 1.0f - p * __expf(-x * x);
    er = __builtin_copysignf(er, v);
    return 0.5f * v * (1.0f + er);
}

// ---------------------------------------------------------------------------
// 1) k_prep: fused grid. Blocks [0,512): fp64 partial mean-reduction over S.
//    Blocks [512,1536): W1 [E][256][512] -> W1T [E][512][256] bf16.
//    Blocks [1536,2560): W2 [E][512][256] -> W2T [E][256][512] bf16.
// ---------------------------------------------------------------------------
__global__ void k_prep(const float* __restrict__ x,
                       double* __restrict__ partial,
                       const float* __restrict__ W1,
                       const float* __restrict__ W2,
                       unsigned short* __restrict__ W1T,
                       unsigned short* __restrict__ W2T) {
    int bid = blockIdx.x;
    if (bid < 512) {
        int b = bid >> 6;
        int c = bid & 63;
        int d = threadIdx.x;
        const float* p = x + ((size_t)(b * S_ + c * 64) * D_ + d);
        double acc = 0.0;
        #pragma unroll 8
        for (int i = 0; i < 64; ++i) acc += (double)p[(size_t)i * D_];
        partial[(size_t)bid * D_ + d] = acc;
        return;
    }
    __shared__ float tile[32][33];
    const float* src;
    unsigned short* dst;
    int R, C, cb, rb;
    if (bid < 1536) {
        int b2 = bid - 512;            // e(8) x by(8) x bx(16)
        int e = b2 >> 7, rem = b2 & 127;
        int by = rem >> 4, bx = rem & 15;
        R = 256; C = 512;
        src = W1 + (size_t)e * R * C;
        dst = W1T + (size_t)e * R * C;
        cb = bx * 32; rb = by * 32;
    } else {
        int b2 = bid - 1536;           // e(8) x by(16) x bx(8)
        int e = b2 >> 7, rem = b2 & 127;
        int by = rem >> 3, bx = rem & 7;
        R = 512; C = 256;
        src = W2 + (size_t)e * R * C;
        dst = W2T + (size_t)e * R * C;
        cb = bx * 32; rb = by * 32;
    }
    int tx = threadIdx.x & 31, ty = threadIdx.x >> 5;
    #pragma unroll
    for (int k = 0; k < 4; ++k)
        tile[ty + 8 * k][tx] = src[(size_t)(rb + ty + 8 * k) * C + cb + tx];
    __syncthreads();
    #pragma unroll
    for (int k = 0; k < 4; ++k)
        dst[(size_t)(cb + ty + 8 * k) * R + rb + tx] = f2bf(tile[tx][ty + 8 * k]);
}

// ---------------------------------------------------------------------------
// 2a) k_red2: 8 blocks (one per batch). Block bb: xs[d] = sum_c partial,
//     then logits lg[bb*8+e] (same fp64 order as before).
// ---------------------------------------------------------------------------
__global__ void k_red2(const double* __restrict__ partial,
                       const float* __restrict__ Wr,
                       const float* __restrict__ br,
                       double* __restrict__ lgout) {
    __shared__ double xs[256];
    int bb = blockIdx.x;
    int t = threadIdx.x;              // 0..255 = d
    double acc = 0.0;
    #pragma unroll 8
    for (int c = 0; c < 64; ++c)
        acc += partial[(size_t)(bb * 64 + c) * D_ + t];
    xs[t] = acc;
    __syncthreads();
    if (t < 8) {
        int e = t;
        double a2 = 0.0;
        for (int d = 0; d < D_; ++d)
            a2 += (xs[d] * (1.0 / (double)S_)) * (double)Wr[d * E_ + e];
        lgout[bb * 8 + e] = a2 + (double)br[e];
    }
}

// ---------------------------------------------------------------------------
// 2b) k_router: 1 tiny block. fp64 phases A/B (unchanged).
// ---------------------------------------------------------------------------
__global__ void k_router(const double* __restrict__ lgin,
                         float* __restrict__ route) {
    __shared__ double lg[64];
    __shared__ double rw[8][8];
    int t = threadIdx.x;
    if (t < 64) lg[t] = lgin[t];
    __syncthreads();
    if (t < 8) {
        int bb = t;
        double m = -1e300;
        for (int ee = 0; ee < 8; ++ee) m = fmax(m, lg[bb * 8 + ee]);
        double s = 0.0;
        double p[8];
        for (int ee = 0; ee < 8; ++ee) { p[ee] = exp(lg[bb * 8 + ee] - m); s += p[ee]; }
        for (int ee = 0; ee < 8; ++ee) rw[bb][ee] = p[ee] / s;
    }
    __syncthreads();
    if (t < 8) {
        int bb = t;
        const double capacity = 5120.0;
        double scale[8];
        for (int ee = 0; ee < 8; ++ee) {
            double load = 0.0;
            for (int b2 = 0; b2 < 8; ++b2) load += rw[b2][ee];
            load *= 4096.0;
            scale[ee] = load > capacity ? capacity / load : 1.0;
        }
        double v[8];
        double m = -1e300;
        for (int ee = 0; ee < 8; ++ee) { v[ee] = rw[bb][ee] * scale[ee]; m = fmax(m, v[ee]); }
        double s = 0.0;
        for (int ee = 0; ee < 8; ++ee) { v[ee] = exp(v[ee] - m); s += v[ee]; }
        for (int ee = 0; ee < 8; ++ee) v[ee] /= s;
        int i1 = 0;
        for (int ee = 1; ee < 8; ++ee) if (v[ee] > v[i1]) i1 = ee;
        int i2 = (i1 == 0) ? 1 : 0;
        for (int ee = 0; ee < 8; ++ee) { if (ee == i1) continue; if (v[ee] > v[i2]) i2 = ee; }
        double d21 = v[i2] - v[i1];
        double ed = exp(d21);
        double w1 = 1.0 / (1.0 + ed);
        double w2 = ed * w1;
        route[bb * 4 + 0] = (float)i1;
        route[bb * 4 + 1] = (float)i2;
        route[bb * 4 + 2] = (float)w1;
        route[bb * 4 + 3] = (float)w2;
    }
}

// ---------------------------------------------------------------------------
// 3) Main MFMA kernel: per block = (batch, 64-token tile). 512 x 512 thr.
//    r14 pipeline (proven 95.7us): flattened it=0..7, per iter:
//      issue w2f(it) -> GEMM1 (swapped: mfma(w1f,x) -> H^T, lane owns 4
//      consecutive f) -> GELU -> ONE b64 Hsb store per mt ->
//      issue w1f(it+1) -> lgkm-barrier -> GEMM2 (w2f long arrived).
//    + s_setprio(1) around both MFMA clusters (T5, 2 indep blocks/CU).
// ---------------------------------------------------------------------------
__launch_bounds__(512, 4)
__global__ void k_moe_m(const float* __restrict__ xf,
                        const unsigned short* __restrict__ W1T,  // [E][F][D]
                        const unsigned short* __restrict__ W2T,  // [E][D][F]
                        const float* __restrict__ b1,
                        const float* __restrict__ b2,
                        const float* __restrict__ gamma,
                        const float* __restrict__ beta,
                        const float* __restrict__ route,
                        float* __restrict__ out) {
    __shared__ __align__(16) unsigned short Xsb[64][264];     // 33.8 KB
    __shared__ __align__(16) unsigned short Hsb[2][64][136];  // 34.8 KB dbuf
    __shared__ float gbuf[256], bbuf[256];
    __shared__ __align__(16) float rred[64][20];              // LN partials

    const int t = threadIdx.x;        // 0..511
    const int wv = t >> 6;            // wave 0..7
    const int lane = t & 63;
    const int g = lane >> 4;          // quad 0..3
    const int c = lane & 15;          // 0..15
    const int b = blockIdx.x & 7;     // XCD-aligned batch (W L2 locality)
    const int m0 = (blockIdx.x >> 3) * 64;

    if (t < 256) { gbuf[t] = gamma[t]; bbuf[t] = beta[t]; }

    const int e0i = (int)route[b * 4 + 0];
    const int e1i = (int)route[b * 4 + 1];
    const float rw0 = route[b * 4 + 2];
    const float rw1 = route[b * 4 + 3];

    // ---- stage X tile [64][256] as bf16, once (cvt_pk: 4 instr / 8 vals) --
    {
        int row = t >> 3;
        int col0 = (t & 7) * 32;
        const float* src = xf + ((size_t)(b * S_ + m0 + row) * D_ + col0);
        #pragma unroll
        for (int jg = 0; jg < 4; ++jg) {
            float4 a0 = *(const float4*)(src + jg * 8);
            float4 a1 = *(const float4*)(src + jg * 8 + 4);
            union { unsigned int pk[4]; uint4 q; } o;
            o.pk[0] = cvt_pk_bf16(a0.x, a0.y);
            o.pk[1] = cvt_pk_bf16(a0.z, a0.w);
            o.pk[2] = cvt_pk_bf16(a1.x, a1.y);
            o.pk[3] = cvt_pk_bf16(a1.z, a1.w);
            *(uint4*)&Xsb[row][col0 + jg * 8] = o.q;
        }
    }

    f32x4 Yacc[4][2];
    #pragma unroll
    for (int i = 0; i < 4; ++i)
        #pragma unroll
        for (int j = 0; j < 2; ++j)
            #pragma unroll
            for (int r = 0; r < 4; ++r) Yacc[i][j][r] = 0.f;

    // ---- prologue: issue w1f for it=0 (hidden under staging + barrier) ----
    bf16x8 w1f[8];
    {
        const unsigned short* w1p0 =
            W1T + ((size_t)(e0i * F_ + wv * 16 + c)) * D_ + g * 8;
        #pragma unroll
        for (int kc = 0; kc < 8; ++kc)
            w1f[kc] = *(const bf16x8*)(w1p0 + kc * 32);
    }

    bar_lds();   // Xsb visible to all waves; pins w1f issue

    int pb = 0;
    for (int it = 0; it < 8; ++it) {
        const int sl = it >> 2;
        const int fb = it & 3;
        const int e = sl ? e1i : e0i;
        const float w = sl ? rw1 : rw0;

        // ---- issue w2f for THIS iteration (first use: GEMM2, far below) --
        const unsigned short* w2p =
            W2T + ((size_t)(e * D_ + wv * 32 + c)) * F_ + fb * 128 + g * 8;
        bf16x8 w2f[4][2];
        #pragma unroll
        for (int kc = 0; kc < 4; ++kc)
            #pragma unroll
            for (int nt = 0; nt < 2; ++nt)
                w2f[kc][nt] = *(const bf16x8*)(w2p + (size_t)(nt * 16) * F_ + kc * 32);

        // bias for this lane's 4 consecutive f rows (H^T ownership)
        float4 bias4 = *(const float4*)&b1[e * F_ + fb * 128 + wv * 16 + g * 4];

        // ---- GEMM1 (swapped): H^T[f][token]; lane holds 4 f x 1 token ----
        f32x4 Hacc[4];
        #pragma unroll
        for (int i = 0; i < 4; ++i)
            #pragma unroll
            for (int r = 0; r < 4; ++r) Hacc[i][r] = 0.f;
        __builtin_amdgcn_s_setprio(1);
        #pragma unroll
        for (int kc = 0; kc < 8; ++kc) {
            #pragma unroll
            for (int mt = 0; mt < 4; ++mt) {
                bf16x8 a = *(const bf16x8*)&Xsb[mt * 16 + c][kc * 32 + g * 8];
                Hacc[mt] = __builtin_amdgcn_mfma_f32_16x16x32_bf16(w1f[kc], a, Hacc[mt], 0, 0, 0);
            }
        }
        __builtin_amdgcn_s_setprio(0);

        // ---- GELU(+b1)*w -> Hsb[pb][token][f], ONE b64 store per mt ----
        #pragma unroll
        for (int mt = 0; mt < 4; ++mt) {
            float h0 = w * gelu_f(Hacc[mt][0] + bias4.x);
            float h1 = w * gelu_f(Hacc[mt][1] + bias4.y);
            float h2 = w * gelu_f(Hacc[mt][2] + bias4.z);
            float h3 = w * gelu_f(Hacc[mt][3] + bias4.w);
            uint2 q;
            q.x = cvt_pk_bf16(h0, h1);
            q.y = cvt_pk_bf16(h2, h3);
            *(uint2*)&Hsb[pb][mt * 16 + c][wv * 16 + g * 4] = q;
        }

        // ---- issue w1f for NEXT iteration (hidden under barrier+GEMM2) ----
        {
            const int itn = (it + 1) & 7;
            const int en = (itn >> 2) ? e1i : e0i;
            const int fbn = itn & 3;
            const unsigned short* w1pn =
                W1T + ((size_t)(en * F_ + fbn * 128 + wv * 16 + c)) * D_ + g * 8;
            #pragma unroll
            for (int kc = 0; kc < 8; ++kc)
                w1f[kc] = *(const bf16x8*)(w1pn + kc * 32);
        }

        bar_lds();   // Hsb[pb] visible; all global loads stay in flight

        // ---- GEMM2: Y[64][256] += Hsb[pb] @ w2f ----
        __builtin_amdgcn_s_setprio(1);
        #pragma unroll
        for (int kc = 0; kc < 4; ++kc) {
            #pragma unroll
            for (int mt = 0; mt < 4; ++mt) {
                bf16x8 a = *(const bf16x8*)&Hsb[pb][mt * 16 + c][kc * 32 + g * 8];
                #pragma unroll
                for (int nt = 0; nt < 2; ++nt)
                    Yacc[mt][nt] = __builtin_amdgcn_mfma_f32_16x16x32_bf16(a, w2f[kc][nt], Yacc[mt][nt], 0, 0, 0);
            }
        }
        __builtin_amdgcn_s_setprio(0);
        pb ^= 1;
    }

    // ---- Epilogue: register LayerNorm ----
    // lane holds Y[row][d]: row = mt*16+g*4+r (16 rows), d = wv*32+nt*16+c.
    float bias2[2];
    #pragma unroll
    for (int nt = 0; nt < 2; ++nt) {
        int d = wv * 32 + nt * 16 + c;
        bias2[nt] = rw0 * b2[e0i * D_ + d] + rw1 * b2[e1i * D_ + d];
    }
    #pragma unroll
    for (int mt = 0; mt < 4; ++mt)
        #pragma unroll
        for (int r = 0; r < 4; ++r) {
            int row = mt * 16 + g * 4 + r;
            const float* xr = xf + (size_t)(b * S_ + m0 + row) * D_;
            float s = 0.f, sq = 0.f;
            #pragma unroll
            for (int nt = 0; nt < 2; ++nt) {
                int d = wv * 32 + nt * 16 + c;
                float v = Yacc[mt][nt][r] + bias2[nt] + xr[d];
                Yacc[mt][nt][r] = v;
                s += v; sq += v * v;
            }
            s += __shfl_xor(s, 1); sq += __shfl_xor(sq, 1);
            s += __shfl_xor(s, 2); sq += __shfl_xor(sq, 2);
            s += __shfl_xor(s, 4); sq += __shfl_xor(sq, 4);
            s += __shfl_xor(s, 8); sq += __shfl_xor(sq, 8);
            if (c == 0) { rred[row][wv * 2] = s; rred[row][wv * 2 + 1] = sq; }
        }
    bar_lds();
    #pragma unroll
    for (int mt = 0; mt < 4; ++mt)
        #pragma unroll
        for (int r = 0; r < 4; ++r) {
            int row = mt * 16 + g * 4 + r;
            float4 p0 = *(const float4*)&rred[row][0];
            float4 p1 = *(const float4*)&rred[row][4];
            float4 p2 = *(const float4*)&rred[row][8];
            float4 p3 = *(const float4*)&rred[row][12];
            float s  = ((p0.x + p1.x) + (p2.x + p3.x)) + ((p0.z + p1.z) + (p2.z + p3.z));
            float sq = ((p0.y + p1.y) + (p2.y + p3.y)) + ((p0.w + p1.w) + (p2.w + p3.w));
            float mu = s * (1.0f / 256.0f);
            float var = sq * (1.0f / 256.0f) - mu * mu;
            float rstd = rsqrtf(var + 1e-5f);
            float* op = out + (size_t)(b * S_ + m0 + row) * D_;
            #pragma unroll
            for (int nt = 0; nt < 2; ++nt) {
                int d = wv * 32 + nt * 16 + c;
                op[d] = (Yacc[mt][nt][r] - mu) * rstd * gbuf[d] + bbuf[d];
            }
        }
}

// ---------------------------------------------------------------------------
extern "C" void kernel_launch(void* const* d_in, const int* in_sizes, int n_in,
                              void* d_out, int out_size, void* d_ws, size_t ws_size,
                              hipStream_t stream) {
    const float* x     = (const float*)d_in[0];
    const float* Wr    = (const float*)d_in[1];
    const float* br    = (const float*)d_in[2];
    const float* W1    = (const float*)d_in[3];
    const float* b1    = (const float*)d_in[4];
    const float* W2    = (const float*)d_in[5];
    const float* b2    = (const float*)d_in[6];
    const float* gamma = (const float*)d_in[7];
    const float* beta  = (const float*)d_in[8];
    float* out = (float*)d_out;

    char* ws = (char*)d_ws;
    double* partial = (double*)ws;                               // 1 MB
    float* route  = (float*)(ws + 1064960);                      // 128 B
    double* lg    = (double*)(ws + 1065472);                     // 512 B
    unsigned short* W1T = (unsigned short*)(ws + 1081344);       // 2 MB [E][F][D]
    unsigned short* W2T = (unsigned short*)(ws + 3178496);       // 2 MB [E][D][F]
    // total ws usage: ~5.3 MB

    hipLaunchKernelGGL(k_prep, dim3(2560), dim3(256), 0, stream,
                       x, partial, W1, W2, W1T, W2T);
    hipLaunchKernelGGL(k_red2, dim3(8), dim3(256), 0, stream,
                       partial, Wr, br, lg);
    hipLaunchKernelGGL(k_router, dim3(1), dim3(64), 0, stream,
                       lg, route);
    hipLaunchKernelGGL(k_moe_m, dim3(512), dim3(512), 0, stream,
                       x, W1T, W2T, b1, b2, gamma, beta, route, out);
}

// Round 12
// 204.081 us; speedup vs baseline: 1.2794x; 1.0005x over previous
//
#include <hip/hip_runtime.h>
#include <math.h>

// ---------------------------------------------------------------------------
// SparseMoE — MFMA kernel, MI355X (gfx950).  B=8 S=4096 D=256 F=512 E=8 K=2.
// r21 = r20 (main kernel byte-identical; confirmed 95.0us, MfmaUtil 14.7,
// no spill) + k_red2/k_router fused into ONE dispatch via the last-block
// pattern (device-scope atomicAdd + __threadfence; winner block re-runs the
// exact k_router phases). Counter zeroed by k_prep block 0 (stream-ordered,
// graph-replay-safe). Session ledger:
//   r15 (32 waves/CU): spill (64-VGPR cap).  r16/r17 (deferred GEMM2):
//   spill (w1f+w2f concurrent liveness >128).  r18 (32x32x16): exposed w2
//   stream + 16-deep acc chains, 154us.  => r14/r20 16x16x32 skeleton with
//   fully-preloaded w2f and 8 independent acc chains is the latency-tolerant
//   optimum; setprio neutral-to-slightly-positive (kept).
// Router fp64 deterministic, identical summation order. ws ~5.3 MB.
// ---------------------------------------------------------------------------

#define B_ 8
#define S_ 4096
#define D_ 256
#define F_ 512
#define E_ 8

typedef short bf16x8 __attribute__((ext_vector_type(8)));
typedef float f32x4 __attribute__((ext_vector_type(4)));

static __device__ __forceinline__ unsigned short f2bf(float f) {
    union { float f; unsigned int i; } v; v.f = f;
    unsigned int x = v.i;
    return (unsigned short)((x + 0x7fffu + ((x >> 16) & 1u)) >> 16);  // RNE
}

// pack two f32 -> two bf16 (RNE), lo = s0, hi = s1
static __device__ __forceinline__ unsigned int cvt_pk_bf16(float s0, float s1) {
    unsigned int r;
    asm("v_cvt_pk_bf16_f32 %0, %1, %2" : "=v"(r) : "v"(s0), "v"(s1));
    return r;
}

// barrier that drains LDS ops only — global loads stay in flight.
static __device__ __forceinline__ void bar_lds() {
    asm volatile("s_waitcnt lgkmcnt(0)" ::: "memory");
    __builtin_amdgcn_s_barrier();
}

// GELU(v) = 0.5 v (1 + erf(v/sqrt2)); erf via A&S 7.1.26, |err|<=1.5e-7.
static __device__ __forceinline__ float gelu_f(float v) {
    float x = fabsf(v) * 0.70710678118654752f;
    float t = __builtin_amdgcn_rcpf(1.0f + 0.3275911f * x);
    float p = t * (0.254829592f +
              t * (-0.284496736f +
              t * (1.421413741f +
              t * (-1.453152027f +
              t * 1.061405429f))));
    float er = 1.0f - p * __expf(-x * x);
    er = __builtin_copysignf(er, v);
    return 0.5f * v * (1.0f + er);
}

// ---------------------------------------------------------------------------
// 1) k_prep: fused grid. Blocks [0,512): fp64 partial mean-reduction over S.
//    Blocks [512,1536): W1 [E][256][512] -> W1T [E][512][256] bf16.
//    Blocks [1536,2560): W2 [E][512][256] -> W2T [E][256][512] bf16.
//    Block 0 thread 0 also zeroes the last-block counter for k_red2r.
// ---------------------------------------------------------------------------
__global__ void k_prep(const float* __restrict__ x,
                       double* __restrict__ partial,
                       const float* __restrict__ W1,
                       const float* __restrict__ W2,
                       unsigned short* __restrict__ W1T,
                       unsigned short* __restrict__ W2T,
                       unsigned int* __restrict__ counter) {
    int bid = blockIdx.x;
    if (bid == 0 && threadIdx.x == 0) *counter = 0u;   // replay-safe reset
    if (bid < 512) {
        int b = bid >> 6;
        int c = bid & 63;
        int d = threadIdx.x;
        const float* p = x + ((size_t)(b * S_ + c * 64) * D_ + d);
        double acc = 0.0;
        #pragma unroll 8
        for (int i = 0; i < 64; ++i) acc += (double)p[(size_t)i * D_];
        partial[(size_t)bid * D_ + d] = acc;
        return;
    }
    __shared__ float tile[32][33];
    const float* src;
    unsigned short* dst;
    int R, C, cb, rb;
    if (bid < 1536) {
        int b2 = bid - 512;            // e(8) x by(8) x bx(16)
        int e = b2 >> 7, rem = b2 & 127;
        int by = rem >> 4, bx = rem & 15;
        R = 256; C = 512;
        src = W1 + (size_t)e * R * C;
        dst = W1T + (size_t)e * R * C;
        cb = bx * 32; rb = by * 32;
    } else {
        int b2 = bid - 1536;           // e(8) x by(16) x bx(8)
        int e = b2 >> 7, rem = b2 & 127;
        int by = rem >> 3, bx = rem & 7;
        R = 512; C = 256;
        src = W2 + (size_t)e * R * C;
        dst = W2T + (size_t)e * R * C;
        cb = bx * 32; rb = by * 32;
    }
    int tx = threadIdx.x & 31, ty = threadIdx.x >> 5;
    #pragma unroll
    for (int k = 0; k < 4; ++k)
        tile[ty + 8 * k][tx] = src[(size_t)(rb + ty + 8 * k) * C + cb + tx];
    __syncthreads();
    #pragma unroll
    for (int k = 0; k < 4; ++k)
        dst[(size_t)(cb + ty + 8 * k) * R + rb + tx] = f2bf(tile[tx][ty + 8 * k]);
}

// ---------------------------------------------------------------------------
// 2) k_red2r: 8 blocks (one per batch). Block bb: xs[d] = sum_c partial,
//    logits lg[bb*8+e] (same fp64 order as r14's k_red2). The LAST block to
//    finish (device-scope atomic) then runs the exact k_router phases A/B.
// ---------------------------------------------------------------------------
__global__ void k_red2r(const double* __restrict__ partial,
                        const float* __restrict__ Wr,
                        const float* __restrict__ br,
                        double* __restrict__ lgout,
                        float* __restrict__ route,
                        unsigned int* __restrict__ counter) {
    __shared__ double xs[256];
    __shared__ double lg[64];
    __shared__ double rw[8][8];
    __shared__ unsigned int lastflag;
    int bb = blockIdx.x;
    int t = threadIdx.x;              // 0..255 = d
    double acc = 0.0;
    #pragma unroll 8
    for (int c = 0; c < 64; ++c)
        acc += partial[(size_t)(bb * 64 + c) * D_ + t];
    xs[t] = acc;
    __syncthreads();
    if (t < 8) {
        int e = t;
        double a2 = 0.0;
        for (int d = 0; d < D_; ++d)
            a2 += (xs[d] * (1.0 / (double)S_)) * (double)Wr[d * E_ + e];
        lgout[bb * 8 + e] = a2 + (double)br[e];
    }
    __threadfence();                  // release this block's lg stores
    __syncthreads();
    if (t == 0) lastflag = (atomicAdd(counter, 1u) == 7u) ? 1u : 0u;
    __syncthreads();
    if (lastflag == 0u) return;       // not last — done
    __threadfence();                  // acquire: see all 64 lg values

    // ---- router (bit-identical to the r14 k_router phases) ----
    if (t < 64) lg[t] = lgout[t];
    __syncthreads();
    if (t < 8) {
        int b2 = t;
        double m = -1e300;
        for (int ee = 0; ee < 8; ++ee) m = fmax(m, lg[b2 * 8 + ee]);
        double s = 0.0;
        double p[8];
        for (int ee = 0; ee < 8; ++ee) { p[ee] = exp(lg[b2 * 8 + ee] - m); s += p[ee]; }
        for (int ee = 0; ee < 8; ++ee) rw[b2][ee] = p[ee] / s;
    }
    __syncthreads();
    if (t < 8) {
        int b2 = t;
        const double capacity = 5120.0;
        double scale[8];
        for (int ee = 0; ee < 8; ++ee) {
            double load = 0.0;
            for (int b3 = 0; b3 < 8; ++b3) load += rw[b3][ee];
            load *= 4096.0;
            scale[ee] = load > capacity ? capacity / load : 1.0;
        }
        double v[8];
        double m = -1e300;
        for (int ee = 0; ee < 8; ++ee) { v[ee] = rw[b2][ee] * scale[ee]; m = fmax(m, v[ee]); }
        double s = 0.0;
        for (int ee = 0; ee < 8; ++ee) { v[ee] = exp(v[ee] - m); s += v[ee]; }
        for (int ee = 0; ee < 8; ++ee) v[ee] /= s;
        int i1 = 0;
        for (int ee = 1; ee < 8; ++ee) if (v[ee] > v[i1]) i1 = ee;
        int i2 = (i1 == 0) ? 1 : 0;
        for (int ee = 0; ee < 8; ++ee) { if (ee == i1) continue; if (v[ee] > v[i2]) i2 = ee; }
        double d21 = v[i2] - v[i1];
        double ed = exp(d21);
        double w1 = 1.0 / (1.0 + ed);
        double w2 = ed * w1;
        route[b2 * 4 + 0] = (float)i1;
        route[b2 * 4 + 1] = (float)i2;
        route[b2 * 4 + 2] = (float)w1;
        route[b2 * 4 + 3] = (float)w2;
    }
}

// ---------------------------------------------------------------------------
// 3) Main MFMA kernel: per block = (batch, 64-token tile). 512 x 512 thr.
//    r14/r20 pipeline (proven 95.0us): flattened it=0..7, per iter:
//      issue w2f(it) -> GEMM1 (swapped: mfma(w1f,x) -> H^T, lane owns 4
//      consecutive f) -> GELU -> ONE b64 Hsb store per mt ->
//      issue w1f(it+1) -> lgkm-barrier -> GEMM2 (w2f long arrived).
//    + s_setprio(1) around both MFMA clusters.
// ---------------------------------------------------------------------------
__launch_bounds__(512, 4)
__global__ void k_moe_m(const float* __restrict__ xf,
                        const unsigned short* __restrict__ W1T,  // [E][F][D]
                        const unsigned short* __restrict__ W2T,  // [E][D][F]
                        const float* __restrict__ b1,
                        const float* __restrict__ b2,
                        const float* __restrict__ gamma,
                        const float* __restrict__ beta,
                        const float* __restrict__ route,
                        float* __restrict__ out) {
    __shared__ __align__(16) unsigned short Xsb[64][264];     // 33.8 KB
    __shared__ __align__(16) unsigned short Hsb[2][64][136];  // 34.8 KB dbuf
    __shared__ float gbuf[256], bbuf[256];
    __shared__ __align__(16) float rred[64][20];              // LN partials

    const int t = threadIdx.x;        // 0..511
    const int wv = t >> 6;            // wave 0..7
    const int lane = t & 63;
    const int g = lane >> 4;          // quad 0..3
    const int c = lane & 15;          // 0..15
    const int b = blockIdx.x & 7;     // XCD-aligned batch (W L2 locality)
    const int m0 = (blockIdx.x >> 3) * 64;

    if (t < 256) { gbuf[t] = gamma[t]; bbuf[t] = beta[t]; }

    const int e0i = (int)route[b * 4 + 0];
    const int e1i = (int)route[b * 4 + 1];
    const float rw0 = route[b * 4 + 2];
    const float rw1 = route[b * 4 + 3];

    // ---- stage X tile [64][256] as bf16, once (cvt_pk: 4 instr / 8 vals) --
    {
        int row = t >> 3;
        int col0 = (t & 7) * 32;
        const float* src = xf + ((size_t)(b * S_ + m0 + row) * D_ + col0);
        #pragma unroll
        for (int jg = 0; jg < 4; ++jg) {
            float4 a0 = *(const float4*)(src + jg * 8);
            float4 a1 = *(const float4*)(src + jg * 8 + 4);
            union { unsigned int pk[4]; uint4 q; } o;
            o.pk[0] = cvt_pk_bf16(a0.x, a0.y);
            o.pk[1] = cvt_pk_bf16(a0.z, a0.w);
            o.pk[2] = cvt_pk_bf16(a1.x, a1.y);
            o.pk[3] = cvt_pk_bf16(a1.z, a1.w);
            *(uint4*)&Xsb[row][col0 + jg * 8] = o.q;
        }
    }

    f32x4 Yacc[4][2];
    #pragma unroll
    for (int i = 0; i < 4; ++i)
        #pragma unroll
        for (int j = 0; j < 2; ++j)
            #pragma unroll
            for (int r = 0; r < 4; ++r) Yacc[i][j][r] = 0.f;

    // ---- prologue: issue w1f for it=0 (hidden under staging + barrier) ----
    bf16x8 w1f[8];
    {
        const unsigned short* w1p0 =
            W1T + ((size_t)(e0i * F_ + wv * 16 + c)) * D_ + g * 8;
        #pragma unroll
        for (int kc = 0; kc < 8; ++kc)
            w1f[kc] = *(const bf16x8*)(w1p0 + kc * 32);
    }

    bar_lds();   // Xsb visible to all waves; pins w1f issue

    int pb = 0;
    for (int it = 0; it < 8; ++it) {
        const int sl = it >> 2;
        const int fb = it & 3;
        const int e = sl ? e1i : e0i;
        const float w = sl ? rw1 : rw0;

        // ---- issue w2f for THIS iteration (first use: GEMM2, far below) --
        const unsigned short* w2p =
            W2T + ((size_t)(e * D_ + wv * 32 + c)) * F_ + fb * 128 + g * 8;
        bf16x8 w2f[4][2];
        #pragma unroll
        for (int kc = 0; kc < 4; ++kc)
            #pragma unroll
            for (int nt = 0; nt < 2; ++nt)
                w2f[kc][nt] = *(const bf16x8*)(w2p + (size_t)(nt * 16) * F_ + kc * 32);

        // bias for this lane's 4 consecutive f rows (H^T ownership)
        float4 bias4 = *(const float4*)&b1[e * F_ + fb * 128 + wv * 16 + g * 4];

        // ---- GEMM1 (swapped): H^T[f][token]; lane holds 4 f x 1 token ----
        f32x4 Hacc[4];
        #pragma unroll
        for (int i = 0; i < 4; ++i)
            #pragma unroll
            for (int r = 0; r < 4; ++r) Hacc[i][r] = 0.f;
        __builtin_amdgcn_s_setprio(1);
        #pragma unroll
        for (int kc = 0; kc < 8; ++kc) {
            #pragma unroll
            for (int mt = 0; mt < 4; ++mt) {
                bf16x8 a = *(const bf16x8*)&Xsb[mt * 16 + c][kc * 32 + g * 8];
                Hacc[mt] = __builtin_amdgcn_mfma_f32_16x16x32_bf16(w1f[kc], a, Hacc[mt], 0, 0, 0);
            }
        }
        __builtin_amdgcn_s_setprio(0);

        // ---- GELU(+b1)*w -> Hsb[pb][token][f], ONE b64 store per mt ----
        #pragma unroll
        for (int mt = 0; mt < 4; ++mt) {
            float h0 = w * gelu_f(Hacc[mt][0] + bias4.x);
            float h1 = w * gelu_f(Hacc[mt][1] + bias4.y);
            float h2 = w * gelu_f(Hacc[mt][2] + bias4.z);
            float h3 = w * gelu_f(Hacc[mt][3] + bias4.w);
            uint2 q;
            q.x = cvt_pk_bf16(h0, h1);
            q.y = cvt_pk_bf16(h2, h3);
            *(uint2*)&Hsb[pb][mt * 16 + c][wv * 16 + g * 4] = q;
        }

        // ---- issue w1f for NEXT iteration (hidden under barrier+GEMM2) ----
        {
            const int itn = (it + 1) & 7;
            const int en = (itn >> 2) ? e1i : e0i;
            const int fbn = itn & 3;
            const unsigned short* w1pn =
                W1T + ((size_t)(en * F_ + fbn * 128 + wv * 16 + c)) * D_ + g * 8;
            #pragma unroll
            for (int kc = 0; kc < 8; ++kc)
                w1f[kc] = *(const bf16x8*)(w1pn + kc * 32);
        }

        bar_lds();   // Hsb[pb] visible; all global loads stay in flight

        // ---- GEMM2: Y[64][256] += Hsb[pb] @ w2f ----
        __builtin_amdgcn_s_setprio(1);
        #pragma unroll
        for (int kc = 0; kc < 4; ++kc) {
            #pragma unroll
            for (int mt = 0; mt < 4; ++mt) {
                bf16x8 a = *(const bf16x8*)&Hsb[pb][mt * 16 + c][kc * 32 + g * 8];
                #pragma unroll
                for (int nt = 0; nt < 2; ++nt)
                    Yacc[mt][nt] = __builtin_amdgcn_mfma_f32_16x16x32_bf16(a, w2f[kc][nt], Yacc[mt][nt], 0, 0, 0);
            }
        }
        __builtin_amdgcn_s_setprio(0);
        pb ^= 1;
    }

    // ---- Epilogue: register LayerNorm ----
    // lane holds Y[row][d]: row = mt*16+g*4+r (16 rows), d = wv*32+nt*16+c.
    float bias2[2];
    #pragma unroll
    for (int nt = 0; nt < 2; ++nt) {
        int d = wv * 32 + nt * 16 + c;
        bias2[nt] = rw0 * b2[e0i * D_ + d] + rw1 * b2[e1i * D_ + d];
    }
    #pragma unroll
    for (int mt = 0; mt < 4; ++mt)
        #pragma unroll
        for (int r = 0; r < 4; ++r) {
            int row = mt * 16 + g * 4 + r;
            const float* xr = xf + (size_t)(b * S_ + m0 + row) * D_;
            float s = 0.f, sq = 0.f;
            #pragma unroll
            for (int nt = 0; nt < 2; ++nt) {
                int d = wv * 32 + nt * 16 + c;
                float v = Yacc[mt][nt][r] + bias2[nt] + xr[d];
                Yacc[mt][nt][r] = v;
                s += v; sq += v * v;
            }
            s += __shfl_xor(s, 1); sq += __shfl_xor(sq, 1);
            s += __shfl_xor(s, 2); sq += __shfl_xor(sq, 2);
            s += __shfl_xor(s, 4); sq += __shfl_xor(sq, 4);
            s += __shfl_xor(s, 8); sq += __shfl_xor(sq, 8);
            if (c == 0) { rred[row][wv * 2] = s; rred[row][wv * 2 + 1] = sq; }
        }
    bar_lds();
    #pragma unroll
    for (int mt = 0; mt < 4; ++mt)
        #pragma unroll
        for (int r = 0; r < 4; ++r) {
            int row = mt * 16 + g * 4 + r;
            float4 p0 = *(const float4*)&rred[row][0];
            float4 p1 = *(const float4*)&rred[row][4];
            float4 p2 = *(const float4*)&rred[row][8];
            float4 p3 = *(const float4*)&rred[row][12];
            float s  = ((p0.x + p1.x) + (p2.x + p3.x)) + ((p0.z + p1.z) + (p2.z + p3.z));
            float sq = ((p0.y + p1.y) + (p2.y + p3.y)) + ((p0.w + p1.w) + (p2.w + p3.w));
            float mu = s * (1.0f / 256.0f);
            float var = sq * (1.0f / 256.0f) - mu * mu;
            float rstd = rsqrtf(var + 1e-5f);
            float* op = out + (size_t)(b * S_ + m0 + row) * D_;
            #pragma unroll
            for (int nt = 0; nt < 2; ++nt) {
                int d = wv * 32 + nt * 16 + c;
                op[d] = (Yacc[mt][nt][r] - mu) * rstd * gbuf[d] + bbuf[d];
            }
        }
}

// ---------------------------------------------------------------------------
extern "C" void kernel_launch(void* const* d_in, const int* in_sizes, int n_in,
                              void* d_out, int out_size, void* d_ws, size_t ws_size,
                              hipStream_t stream) {
    const float* x     = (const float*)d_in[0];
    const float* Wr    = (const float*)d_in[1];
    const float* br    = (const float*)d_in[2];
    const float* W1    = (const float*)d_in[3];
    const float* b1    = (const float*)d_in[4];
    const float* W2    = (const float*)d_in[5];
    const float* b2    = (const float*)d_in[6];
    const float* gamma = (const float*)d_in[7];
    const float* beta  = (const float*)d_in[8];
    float* out = (float*)d_out;

    char* ws = (char*)d_ws;
    double* partial = (double*)ws;                               // 1 MB
    float* route  = (float*)(ws + 1064960);                      // 128 B
    double* lg    = (double*)(ws + 1065472);                     // 512 B
    unsigned int* counter = (unsigned int*)(ws + 1066496);       // 4 B
    unsigned short* W1T = (unsigned short*)(ws + 1081344);       // 2 MB [E][F][D]
    unsigned short* W2T = (unsigned short*)(ws + 3178496);       // 2 MB [E][D][F]
    // total ws usage: ~5.3 MB

    hipLaunchKernelGGL(k_prep, dim3(2560), dim3(256), 0, stream,
                       x, partial, W1, W2, W1T, W2T, counter);
    hipLaunchKernelGGL(k_red2r, dim3(8), dim3(256), 0, stream,
                       partial, Wr, br, lg, route, counter);
    hipLaunchKernelGGL(k_moe_m, dim3(512), dim3(512), 0, stream,
                       x, W1T, W2T, b1, b2, gamma, beta, route, out);
}